// Round 5
// baseline (1484.890 us; speedup 1.0000x reference)
//
#include <hip/hip_runtime.h>
#include <hip/hip_bf16.h>

// GptOss grouped experts, round 5: faithful m201 8-phase-style schedule.
// BM=256 x BN=192, BK=64, 8 waves (2M x 4N), per-wave 128x48 (FM=8, FN=3).
// 4 phases per K-tile, each {ds_reads + 2-3 global_load_lds -> barrier ->
// lgkmcnt(0) -> setprio(1) -> 12 MFMA -> setprio(0) -> barrier}.
// Stage units split by wave-read order: A-lo = row units {0,2} (freed after
// ph1 -> staged 1.5 tiles ahead), A-hi = {1,3}@ph0, B@ph1. One counted
// vmcnt(2) per K-tile at ph3 end. T1 XCD swizzle, T2 XOR swizzle
// (inverse-swizzled global source), T5 setprio. SwiGLU fused in GEMM1.

#define TT   16384
#define DIM_ 2880
#define HID_ 2880
#define NE   8
#define TPE  2048
#define KDIM 2880
#define NT   45     // KDIM / 64

typedef __attribute__((ext_vector_type(8))) short short8;
typedef __attribute__((ext_vector_type(4))) float f32x4;

__device__ __forceinline__ unsigned short f2bf(float f) {
  unsigned u = __builtin_bit_cast(unsigned, f);
  u += 0x7fffu + ((u >> 16) & 1u);   // round-to-nearest-even
  return (unsigned short)(u >> 16);
}

__global__ void __launch_bounds__(256) cvt_f32_bf16(const float* __restrict__ src,
                                                    unsigned short* __restrict__ dst,
                                                    long n) {
  long i = ((long)blockIdx.x * 256 + threadIdx.x) * 8;
  if (i >= n) return;
  float4 a = *(const float4*)(src + i);
  float4 b = *(const float4*)(src + i + 4);
  union { unsigned short u[8]; short8 v; } r;
  r.u[0] = f2bf(a.x); r.u[1] = f2bf(a.y); r.u[2] = f2bf(a.z); r.u[3] = f2bf(a.w);
  r.u[4] = f2bf(b.x); r.u[5] = f2bf(b.y); r.u[6] = f2bf(b.z); r.u[7] = f2bf(b.w);
  *(short8*)(dst + i) = r.v;
}

#define GLDS(gsrc, ldst) \
  __builtin_amdgcn_global_load_lds( \
      (const __attribute__((address_space(1))) unsigned int*)(gsrc), \
      (__attribute__((address_space(3))) unsigned int*)(ldst), 16, 0, 0)

// C = A(MxK) * B(NxK)^T, bf16 in, fp32 accum.
// Grid: (ntm*ntn, 1, E). LDS: dbuf x (A 32KB + B 24KB) = 112 KB.
template<bool FUSE_SWIGLU>
__global__ void __launch_bounds__(512, 2) gemm8p(const unsigned short* __restrict__ A,
                                                 const unsigned short* __restrict__ B,
                                                 const float* __restrict__ bias,
                                                 void* __restrict__ Cout,
                                                 int M, int N) {
  __shared__ unsigned short As[2][256 * 64];
  __shared__ unsigned short Bs[2][192 * 64];

  const int tid  = threadIdx.x;
  const int lane = tid & 63;
  const int wid  = tid >> 6;
  const int wr   = wid >> 2;        // 0..1
  const int wc   = wid & 3;         // 0..3
  const int e    = blockIdx.z;

  // T1: per-expert bijective XCD swizzle (per_e = 240 / 120, both %8 == 0).
  const int ntn   = N / 192;
  const int ntm   = M / 256;
  const int per_e = ntn * ntm;
  const int bid   = blockIdx.x;
  const int swz   = (bid & 7) * (per_e >> 3) + (bid >> 3);
  const int m0    = (swz / ntn) * 256;
  const int n0    = (swz % ntn) * 192;

  // staging: 8 lanes/row, 16B/lane; T2 inverse-swizzle on source column
  const int srow = tid >> 3;                         // 0..63
  const int scol = ((tid & 7) ^ (srow & 7)) << 3;    // elements
  const unsigned short* Aexp = A + ((size_t)e * M + m0 + srow) * KDIM + scol;
  const unsigned short* Bexp = B + ((size_t)e * N + n0 + srow) * KDIM + scol;

  // stage unit j = rows [64j, 64j+64). A-lo (read by fm0-3 of both wave-rows)
  // = units {0,2}; A-hi = units {1,3}; B = units {0,1,2}.
  auto stageA2 = [&](int buf, int kt, int ja, int jb) {
    const unsigned short* src = Aexp + (size_t)kt * 64;
    GLDS(src + (size_t)(ja * 64) * KDIM, &As[buf][ja * 4096 + tid * 8]);
    GLDS(src + (size_t)(jb * 64) * KDIM, &As[buf][jb * 4096 + tid * 8]);
  };
  auto stageB3 = [&](int buf, int kt) {
    const unsigned short* src = Bexp + (size_t)kt * 64;
#pragma unroll
    for (int j = 0; j < 3; ++j)
      GLDS(src + (size_t)(j * 64) * KDIM, &Bs[buf][j * 4096 + tid * 8]);
  };

  // fragment-read addressing (swizzled), byte offsets; row stride 128 B
  const int arow = (wr * 128 + (lane & 15)) * 128;
  const int brow = (wc * 48  + (lane & 15)) * 128;
  const int swzb = (lane & 7) << 4;
  const int kb   = ((lane >> 4) & 3) * 16;
  const int c0 = kb ^ swzb;          // kk=0
  const int c1 = (64 + kb) ^ swzb;   // kk=1

  f32x4 acc[8][3] = {};
  short8 a[4], b0[3], b1[3];

  // prologue: tile0 full (7 loads) + A-lo(1) (2 loads); wait tile0.
  stageA2(0, 0, 0, 1); stageA2(0, 0, 2, 3);
  stageB3(0, 0);
  stageA2(1, 1, 0, 2);
  asm volatile("s_waitcnt vmcnt(2)" ::: "memory");
  __builtin_amdgcn_s_barrier();

  for (int t = 0; t < NT; ++t) {
    const int cur = t & 1;
    const char* aB = (const char*)(&As[cur][0]) + arow;
    const char* bB = (const char*)(&Bs[cur][0]) + brow;
    const bool n1ok = (t + 1 < NT);
    const bool n2ok = (t + 2 < NT);

    // ---- ph0: read A-lo kk0 + B kk0; stage A-hi(t+1) -> buf cur^1
#pragma unroll
    for (int i = 0; i < 4; ++i) a[i]  = *(const short8*)(aB + i * 2048 + c0);
#pragma unroll
    for (int f = 0; f < 3; ++f) b0[f] = *(const short8*)(bB + f * 2048 + c0);
    if (n1ok) stageA2(cur ^ 1, t + 1, 1, 3);
    __builtin_amdgcn_s_barrier();
    asm volatile("s_waitcnt lgkmcnt(0)" ::: "memory");
    __builtin_amdgcn_s_setprio(1);
#pragma unroll
    for (int f = 0; f < 3; ++f)
#pragma unroll
      for (int i = 0; i < 4; ++i)
        acc[i][f] = __builtin_amdgcn_mfma_f32_16x16x32_bf16(a[i], b0[f], acc[i][f], 0, 0, 0);
    __builtin_amdgcn_s_setprio(0);
    __builtin_amdgcn_s_barrier();

    // ---- ph1: read A-lo kk1 + B kk1; stage B(t+1) -> buf cur^1
#pragma unroll
    for (int i = 0; i < 4; ++i) a[i]  = *(const short8*)(aB + i * 2048 + c1);
#pragma unroll
    for (int f = 0; f < 3; ++f) b1[f] = *(const short8*)(bB + f * 2048 + c1);
    if (n1ok) stageB3(cur ^ 1, t + 1);
    __builtin_amdgcn_s_barrier();
    asm volatile("s_waitcnt lgkmcnt(0)" ::: "memory");
    __builtin_amdgcn_s_setprio(1);
#pragma unroll
    for (int f = 0; f < 3; ++f)
#pragma unroll
      for (int i = 0; i < 4; ++i)
        acc[i][f] = __builtin_amdgcn_mfma_f32_16x16x32_bf16(a[i], b1[f], acc[i][f], 0, 0, 0);
    __builtin_amdgcn_s_setprio(0);
    __builtin_amdgcn_s_barrier();
    // A-lo units of buf cur now fully read by all waves

    // ---- ph2: read A-hi kk0 (B kk0 still in regs); stage A-lo(t+2) -> buf cur
#pragma unroll
    for (int i = 0; i < 4; ++i) a[i] = *(const short8*)(aB + (4 + i) * 2048 + c0);
    if (n2ok) stageA2(cur, t + 2, 0, 2);
    __builtin_amdgcn_s_barrier();
    asm volatile("s_waitcnt lgkmcnt(0)" ::: "memory");
    __builtin_amdgcn_s_setprio(1);
#pragma unroll
    for (int f = 0; f < 3; ++f)
#pragma unroll
      for (int i = 0; i < 4; ++i)
        acc[4 + i][f] = __builtin_amdgcn_mfma_f32_16x16x32_bf16(a[i], b0[f], acc[4 + i][f], 0, 0, 0);
    __builtin_amdgcn_s_setprio(0);
    __builtin_amdgcn_s_barrier();

    // ---- ph3: read A-hi kk1 (B kk1 in regs); vmcnt(2) -> tile t+1 ready
#pragma unroll
    for (int i = 0; i < 4; ++i) a[i] = *(const short8*)(aB + (4 + i) * 2048 + c1);
    __builtin_amdgcn_s_barrier();
    asm volatile("s_waitcnt lgkmcnt(0)" ::: "memory");
    __builtin_amdgcn_s_setprio(1);
#pragma unroll
    for (int f = 0; f < 3; ++f)
#pragma unroll
      for (int i = 0; i < 4; ++i)
        acc[4 + i][f] = __builtin_amdgcn_mfma_f32_16x16x32_bf16(a[i], b1[f], acc[4 + i][f], 0, 0, 0);
    __builtin_amdgcn_s_setprio(0);
    if (n2ok) asm volatile("s_waitcnt vmcnt(2)" ::: "memory");
    else      asm volatile("s_waitcnt vmcnt(0)" ::: "memory");
    __builtin_amdgcn_s_barrier();
  }

  // ---- epilogue
  const float* be = bias + (size_t)e * N;
  if constexpr (FUSE_SWIGLU) {
    unsigned short* ha = (unsigned short*)Cout + (size_t)e * M * (N >> 1);
#pragma unroll
    for (int fm = 0; fm < 8; ++fm)
#pragma unroll
      for (int fn = 0; fn < 3; ++fn) {
        const int col = n0 + wc * 48 + fn * 16 + (lane & 15);
        const float bc = be[col];
#pragma unroll
        for (int j = 0; j < 4; ++j) {
          const int row = m0 + wr * 128 + fm * 16 + (lane >> 4) * 4 + j;
          float v = acc[fm][fn][j] + bc;
          float p = __shfl_xor(v, 1);   // partner column (all lanes execute)
          if (!(lane & 1)) {
            float g  = fminf(v, 7.0f);
            float l2 = fminf(fmaxf(p, -7.0f), 7.0f);
            float act = g / (1.0f + __expf(-1.702f * g)) * (l2 + 1.0f);
            ha[(size_t)row * (N >> 1) + (col >> 1)] = f2bf(act);
          }
        }
      }
  } else {
    float* out = (float*)Cout + (size_t)e * M * N;
#pragma unroll
    for (int fm = 0; fm < 8; ++fm)
#pragma unroll
      for (int fn = 0; fn < 3; ++fn) {
        const int col = n0 + wc * 48 + fn * 16 + (lane & 15);
        const float bc = be[col];
#pragma unroll
        for (int j = 0; j < 4; ++j) {
          const int row = m0 + wr * 128 + fm * 16 + (lane >> 4) * 4 + j;
          out[(size_t)row * N + col] = acc[fm][fn][j] + bc;
        }
      }
  }
}

extern "C" void kernel_launch(void* const* d_in, const int* in_sizes, int n_in,
                              void* d_out, int out_size, void* d_ws, size_t ws_size,
                              hipStream_t stream) {
  const float* x  = (const float*)d_in[0];
  // d_in[1] = num_tokens_per_expert: fixed T/E split (reference ignores it)
  const float* w1 = (const float*)d_in[2];
  const float* b1 = (const float*)d_in[3];
  const float* w2 = (const float*)d_in[4];
  const float* b2 = (const float*)d_in[5];

  unsigned short* xb  = (unsigned short*)d_ws;
  unsigned short* w1b = xb  + (size_t)TT * DIM_;
  unsigned short* w2b = w1b + (size_t)NE * 2 * HID_ * DIM_;
  unsigned short* ha  = w2b + (size_t)NE * DIM_ * HID_;

  const long nx = (long)TT * DIM_;
  const long n1 = (long)NE * 2 * HID_ * DIM_;
  const long n2 = (long)NE * DIM_ * HID_;
  cvt_f32_bf16<<<(int)(nx / 2048), 256, 0, stream>>>(x,  xb,  nx);
  cvt_f32_bf16<<<(int)(n1 / 2048), 256, 0, stream>>>(w1, w1b, n1);
  cvt_f32_bf16<<<(int)(n2 / 2048), 256, 0, stream>>>(w2, w2b, n2);

  // GEMM1 + bias + swiglu -> ha (bf16 [E][2048][2880])
  dim3 g1((5760 / 192) * (TPE / 256), 1, NE);   // 240 per expert
  gemm8p<true><<<g1, 512, 0, stream>>>(xb, w1b, b1, ha, TPE, 5760);

  // GEMM2 + bias -> out (fp32 [T][2880])
  dim3 g2((DIM_ / 192) * (TPE / 256), 1, NE);   // 120 per expert
  gemm8p<false><<<g2, 512, 0, stream>>>(ha, w2b, b2, (float*)d_out, TPE, DIM_);
}

// Round 7
// 1177.788 us; speedup vs baseline: 1.2607x; 1.2607x over previous
//
#include <hip/hip_runtime.h>
#include <hip/hip_bf16.h>

// GptOss grouped experts, round 6 resubmit (infra failure, kernel unchanged):
// R3's verified 2-barrier counted-vmcnt structure, parameter change only:
// BN 192 -> 320 (FN=5, per-wave 128x80) to amortize the fixed per-K-tile
// stall over 80 instead of 48 MFMA. 5760 and 2880 both divide by 320 ->
// no padding. LDS 144 KB dbuf. T1 XCD swizzle, T2 XOR swizzle
// (inverse-swizzled global source), T5 setprio on kk1 cluster.
// SwiGLU fused into GEMM1 epilogue. fp32->bf16 pre-convert in d_ws.

#define TT   16384
#define DIM_ 2880
#define HID_ 2880
#define NE   8
#define TPE  2048
#define KDIM 2880
#define NT   45     // KDIM / 64

typedef __attribute__((ext_vector_type(8))) short short8;
typedef __attribute__((ext_vector_type(4))) float f32x4;

__device__ __forceinline__ unsigned short f2bf(float f) {
  unsigned u = __builtin_bit_cast(unsigned, f);
  u += 0x7fffu + ((u >> 16) & 1u);   // round-to-nearest-even
  return (unsigned short)(u >> 16);
}

__global__ void __launch_bounds__(256) cvt_f32_bf16(const float* __restrict__ src,
                                                    unsigned short* __restrict__ dst,
                                                    long n) {
  long i = ((long)blockIdx.x * 256 + threadIdx.x) * 8;
  if (i >= n) return;
  float4 a = *(const float4*)(src + i);
  float4 b = *(const float4*)(src + i + 4);
  union { unsigned short u[8]; short8 v; } r;
  r.u[0] = f2bf(a.x); r.u[1] = f2bf(a.y); r.u[2] = f2bf(a.z); r.u[3] = f2bf(a.w);
  r.u[4] = f2bf(b.x); r.u[5] = f2bf(b.y); r.u[6] = f2bf(b.z); r.u[7] = f2bf(b.w);
  *(short8*)(dst + i) = r.v;
}

#define GLDS(gsrc, ldst) \
  __builtin_amdgcn_global_load_lds( \
      (const __attribute__((address_space(1))) unsigned int*)(gsrc), \
      (__attribute__((address_space(3))) unsigned int*)(ldst), 16, 0, 0)

// C = A(MxK) * B(NxK)^T, bf16 in, fp32 accum. BM=256, BN=320, BK=64.
// 512 threads = 8 waves (2M x 4N); per-wave 128x80 (FM=8, FN=5).
// Grid: (ntm*ntn, 1, E). LDS: dbuf x (A 32KB + B 40KB) = 144 KB.
template<bool FUSE_SWIGLU>
__global__ void __launch_bounds__(512, 2) gemm8(const unsigned short* __restrict__ A,
                                                const unsigned short* __restrict__ B,
                                                const float* __restrict__ bias,
                                                void* __restrict__ Cout,
                                                int M, int N) {
  __shared__ unsigned short As[2][256 * 64];
  __shared__ unsigned short Bs[2][320 * 64];

  const int tid  = threadIdx.x;
  const int lane = tid & 63;
  const int wid  = tid >> 6;
  const int wr   = wid >> 2;        // 0..1
  const int wc   = wid & 3;         // 0..3
  const int e    = blockIdx.z;

  // T1: per-expert bijective XCD swizzle (per_e = 144 / 72, both %8 == 0).
  const int ntn   = N / 320;
  const int ntm   = M / 256;
  const int per_e = ntn * ntm;
  const int bid   = blockIdx.x;
  const int swz   = (bid & 7) * (per_e >> 3) + (bid >> 3);
  const int m0    = (swz / ntn) * 256;
  const int n0    = (swz % ntn) * 320;

  // staging: 8 lanes/row, 16B/lane; T2 inverse-swizzle on source column
  const int srow = tid >> 3;                         // 0..63
  const int scol = ((tid & 7) ^ (srow & 7)) << 3;    // elements
  const unsigned short* Aexp = A + ((size_t)e * M + m0 + srow) * KDIM + scol;
  const unsigned short* Bexp = B + ((size_t)e * N + n0 + srow) * KDIM + scol;

  auto stage = [&](int buf, int kt) {
    const unsigned short* asrc = Aexp + (size_t)kt * 64;
#pragma unroll
    for (int j = 0; j < 4; ++j)
      GLDS(asrc + (size_t)(j * 64) * KDIM, &As[buf][j * 4096 + tid * 8]);
    const unsigned short* bsrc = Bexp + (size_t)kt * 64;
#pragma unroll
    for (int j = 0; j < 5; ++j)
      GLDS(bsrc + (size_t)(j * 64) * KDIM, &Bs[buf][j * 4096 + tid * 8]);
  };

  // fragment-read addressing (swizzled), byte offsets; row stride 128 B
  const int arow = (wr * 128 + (lane & 15)) * 128;
  const int brow = (wc * 80  + (lane & 15)) * 128;
  const int swzb = (lane & 7) << 4;
  const int kb   = ((lane >> 4) & 3) * 16;
  const int c0 = kb ^ swzb;          // kk=0
  const int c1 = (64 + kb) ^ swzb;   // kk=1

  f32x4 acc[8][5] = {};

  // prologue: tiles 0,1 staged (9 loads each); wait tile 0.
  stage(0, 0);
  stage(1, 1);
  asm volatile("s_waitcnt vmcnt(9)" ::: "memory");
  __builtin_amdgcn_s_barrier();

  for (int t = 0; t < NT; ++t) {
    const int cur = t & 1;
    const char* aB = (const char*)(&As[cur][0]) + arow;
    const char* bB = (const char*)(&Bs[cur][0]) + brow;

    short8 a0[8], a1[8], b0[5], b1[5];
#pragma unroll
    for (int fm = 0; fm < 8; ++fm) {
      a0[fm] = *(const short8*)(aB + fm * 2048 + c0);
      a1[fm] = *(const short8*)(aB + fm * 2048 + c1);
    }
#pragma unroll
    for (int fn = 0; fn < 5; ++fn) {
      b0[fn] = *(const short8*)(bB + fn * 2048 + c0);
      b1[fn] = *(const short8*)(bB + fn * 2048 + c1);
    }

    // kk=0 MFMAs overlap kk=1 ds_reads (compiler counted lgkmcnt)
#pragma unroll
    for (int fn = 0; fn < 5; ++fn)
#pragma unroll
      for (int fm = 0; fm < 8; ++fm)
        acc[fm][fn] = __builtin_amdgcn_mfma_f32_16x16x32_bf16(a0[fm], b0[fn], acc[fm][fn], 0, 0, 0);

    // all our ds_reads done -> buffer free; barrier makes it true for all waves
    asm volatile("s_waitcnt lgkmcnt(0)" ::: "memory");
    __builtin_amdgcn_s_barrier();

    const bool more = (t + 2 < NT);
    if (more) stage(cur, t + 2);     // overwrite vacated buffer

    __builtin_amdgcn_s_setprio(1);
#pragma unroll
    for (int fn = 0; fn < 5; ++fn)
#pragma unroll
      for (int fm = 0; fm < 8; ++fm)
        acc[fm][fn] = __builtin_amdgcn_mfma_f32_16x16x32_bf16(a1[fm], b1[fn], acc[fm][fn], 0, 0, 0);
    __builtin_amdgcn_s_setprio(0);

    // counted vmcnt: wait tile t+1 complete, leave tile t+2's 9 loads in flight
    if (more) asm volatile("s_waitcnt vmcnt(9)" ::: "memory");
    else      asm volatile("s_waitcnt vmcnt(0)" ::: "memory");
    __builtin_amdgcn_s_barrier();
  }

  // ---- epilogue
  const float* be = bias + (size_t)e * N;
  if constexpr (FUSE_SWIGLU) {
    unsigned short* ha = (unsigned short*)Cout + (size_t)e * M * (N >> 1);
#pragma unroll
    for (int fm = 0; fm < 8; ++fm)
#pragma unroll
      for (int fn = 0; fn < 5; ++fn) {
        const int col = n0 + wc * 80 + fn * 16 + (lane & 15);
        const float bc = be[col];
#pragma unroll
        for (int j = 0; j < 4; ++j) {
          const int row = m0 + wr * 128 + fm * 16 + (lane >> 4) * 4 + j;
          float v = acc[fm][fn][j] + bc;
          float p = __shfl_xor(v, 1);   // partner column (all lanes execute)
          if (!(lane & 1)) {
            float g  = fminf(v, 7.0f);
            float l2 = fminf(fmaxf(p, -7.0f), 7.0f);
            float act = g / (1.0f + __expf(-1.702f * g)) * (l2 + 1.0f);
            ha[(size_t)row * (N >> 1) + (col >> 1)] = f2bf(act);
          }
        }
      }
  } else {
    float* out = (float*)Cout + (size_t)e * M * N;
#pragma unroll
    for (int fm = 0; fm < 8; ++fm)
#pragma unroll
      for (int fn = 0; fn < 5; ++fn) {
        const int col = n0 + wc * 80 + fn * 16 + (lane & 15);
        const float bc = be[col];
#pragma unroll
        for (int j = 0; j < 4; ++j) {
          const int row = m0 + wr * 128 + fm * 16 + (lane >> 4) * 4 + j;
          out[(size_t)row * N + col] = acc[fm][fn][j] + bc;
        }
      }
  }
}

extern "C" void kernel_launch(void* const* d_in, const int* in_sizes, int n_in,
                              void* d_out, int out_size, void* d_ws, size_t ws_size,
                              hipStream_t stream) {
  const float* x  = (const float*)d_in[0];
  // d_in[1] = num_tokens_per_expert: fixed T/E split (reference ignores it)
  const float* w1 = (const float*)d_in[2];
  const float* b1 = (const float*)d_in[3];
  const float* w2 = (const float*)d_in[4];
  const float* b2 = (const float*)d_in[5];

  unsigned short* xb  = (unsigned short*)d_ws;
  unsigned short* w1b = xb  + (size_t)TT * DIM_;
  unsigned short* w2b = w1b + (size_t)NE * 2 * HID_ * DIM_;
  unsigned short* ha  = w2b + (size_t)NE * DIM_ * HID_;

  const long nx = (long)TT * DIM_;
  const long n1 = (long)NE * 2 * HID_ * DIM_;
  const long n2 = (long)NE * DIM_ * HID_;
  cvt_f32_bf16<<<(int)(nx / 2048), 256, 0, stream>>>(x,  xb,  nx);
  cvt_f32_bf16<<<(int)(n1 / 2048), 256, 0, stream>>>(w1, w1b, n1);
  cvt_f32_bf16<<<(int)(n2 / 2048), 256, 0, stream>>>(w2, w2b, n2);

  // GEMM1 + bias + swiglu -> ha (bf16 [E][2048][2880])
  dim3 g1((5760 / 320) * (TPE / 256), 1, NE);   // 18*8 = 144 per expert
  gemm8<true><<<g1, 512, 0, stream>>>(xb, w1b, b1, ha, TPE, 5760);

  // GEMM2 + bias -> out (fp32 [T][2880])
  dim3 g2((DIM_ / 320) * (TPE / 256), 1, NE);   // 9*8 = 72 per expert
  gemm8<false><<<g2, 512, 0, stream>>>(ha, w2b, b2, (float*)d_out, TPE, DIM_);
}